// Round 1
// baseline (561.383 us; speedup 1.0000x reference)
//
#include <hip/hip_runtime.h>
#include <hip/hip_bf16.h>

// Problem constants
#define B_    65536
#define A_    8
#define S_    128
#define ADIM_ 16
#define H_    64
#define IN_   144
#define H3_   192
#define NROW  (B_*A_)   // 524288

typedef __attribute__((ext_vector_type(8))) short bf16x8;
typedef __attribute__((ext_vector_type(4))) float f32x4;

// ---- packed weight fragment table (bf16, MFMA A-operand layout) ----
// frag = 64 lanes x 8 bf16 = 1024 B. lane l holds W[k][n] for
// k = kt*32 + (l>>4)*8 + i, n = mt*16 + (l&15).
#define F_ENC 20   // kt 0..4, mt 0..3
#define F_OBS 8    // kt 0..1, mt 0..3
#define F_WI  24   // kt 0..1, mt 0..11
#define F_WH  24
#define OFF_ENC 0
#define OFF_OBS (F_ENC)
#define OFF_WI  (F_ENC+F_OBS)
#define OFF_WH  (F_ENC+F_OBS+F_WI)
#define NFRAG   (F_ENC+F_OBS+F_WI+F_WH)  // 76

__device__ __forceinline__ unsigned short f2bf(float f){
  union{float f; unsigned u;} v; v.f=f;
  unsigned r = (v.u + 0x7FFFu + ((v.u>>16)&1u))>>16;   // RNE
  return (unsigned short)r;
}
__device__ __forceinline__ float bf2f(unsigned short s){
  union{float f; unsigned u;} v; v.u = ((unsigned)s)<<16; return v.f;
}
__device__ __forceinline__ float sigmoidf_(float x){
  float e = __expf(-x);
  return __builtin_amdgcn_rcpf(1.f + e);
}
__device__ __forceinline__ float tanhf_(float x){
  float e = __expf(2.f*x);
  return 1.f - 2.f*__builtin_amdgcn_rcpf(e + 1.f);
}
__device__ __forceinline__ f32x4 MFMA(bf16x8 a, bf16x8 b, f32x4 c){
  return __builtin_amdgcn_mfma_f32_16x16x32_bf16(a, b, c, 0, 0, 0);
}
__device__ __forceinline__ f32x4 zero4(){ f32x4 v; v[0]=v[1]=v[2]=v[3]=0.f; return v; }
__device__ __forceinline__ bf16x8 zero8(){ bf16x8 v;
#pragma unroll
  for (int i=0;i<8;i++) v[i]=0; return v; }

// ---------------- weight pre-pack kernel (runs every launch) -------------
__global__ __launch_bounds__(64) void pack_weights(
    const float* __restrict__ We, const float* __restrict__ Wo,
    const float* __restrict__ Wi, const float* __restrict__ Wh,
    unsigned short* __restrict__ pw)
{
  int f = blockIdx.x, lane = threadIdx.x;
  const float* W; int K, NC, kt, mt;
  if (f < OFF_OBS)      { W=We; K=IN_; NC=H_;  int fi=f;         kt=fi>>2;  mt=fi&3;  }
  else if (f < OFF_WI)  { W=Wo; K=H_;  NC=H_;  int fi=f-OFF_OBS; kt=fi>>2;  mt=fi&3;  }
  else if (f < OFF_WH)  { W=Wi; K=H_;  NC=H3_; int fi=f-OFF_WI;  kt=fi/12;  mt=fi%12; }
  else                  { W=Wh; K=H_;  NC=H3_; int fi=f-OFF_WH;  kt=fi/12;  mt=fi%12; }
  int g = lane>>4, l15 = lane&15;
  bf16x8 v;
#pragma unroll
  for (int i=0;i<8;i++){
    int k = kt*32 + g*8 + i;
    int n = mt*16 + l15;
    float x = (k < K) ? W[(size_t)k*NC + n] : 0.f;
    v[i] = (short)f2bf(x);
  }
  *(bf16x8*)(pw + (size_t)f*512 + lane*8) = v;
}

// ---------------- fused critic kernel -----------------------------------
// 256 thr = 4 waves; each wave owns 32 rows (2 MFMA N-tiles of 16 rows = 2x2
// complete agent batches). All GEMMs computed transposed: D^T = W^T * x^T,
// so lanes hold (outcol-slice, own-row) and GRU elementwise is lane-local.
__global__ __launch_bounds__(256) void critic_main(
    const float* __restrict__ obs, const float* __restrict__ act,
    const float* __restrict__ b_enc, const float* __restrict__ b_obs,
    const float* __restrict__ bi,    const float* __restrict__ bh,
    const float* __restrict__ wdec,  const float* __restrict__ bdec,
    const unsigned short* __restrict__ pw, float* __restrict__ out)
{
  // per-wave double buffers: [wave][u][pingpong][16 rows][72 cols] bf16
  __shared__ unsigned short buf[4][2][2][16*72];
  __shared__ float Sbuf[4][2][2][64];   // [wave][u][batch-in-tile][col]

  const int tid = threadIdx.x, wid = tid>>6, lane = tid&63;
  const int g = lane>>4, l15 = lane&15;
  const size_t rb = ((size_t)blockIdx.x*4 + wid)*32;
  const bf16x8* pf = (const bf16x8*)pw;   // frag f, lane l at pf[f*64+l]

  // ======== Stage E: e = relu([obs|act] @ W_enc + b_enc) ========
  f32x4 acc[2][4];
#pragma unroll
  for (int u=0;u<2;u++)
#pragma unroll
    for (int mt=0;mt<4;mt++) acc[u][mt] = zero4();

#pragma unroll
  for (int kt=0; kt<5; kt++){
    bf16x8 xf[2];
#pragma unroll
    for (int u=0;u<2;u++){
      size_t row = rb + u*16 + l15;
      if (kt < 4){
        const f32x4* p = (const f32x4*)(obs + row*S_ + kt*32 + g*8);
        f32x4 a = p[0], b = p[1];
        bf16x8 t;
#pragma unroll
        for (int i=0;i<4;i++){ t[i] = (short)f2bf(a[i]); t[i+4] = (short)f2bf(b[i]); }
        xf[u] = t;
      } else if (g < 2){
        const f32x4* p = (const f32x4*)(act + row*ADIM_ + g*8);
        f32x4 a = p[0], b = p[1];
        bf16x8 t;
#pragma unroll
        for (int i=0;i<4;i++){ t[i] = (short)f2bf(a[i]); t[i+4] = (short)f2bf(b[i]); }
        xf[u] = t;
      } else {
        xf[u] = zero8();
      }
    }
#pragma unroll
    for (int mt=0;mt<4;mt++){
      bf16x8 wf = pf[(OFF_ENC + kt*4 + mt)*64 + lane];
      acc[0][mt] = MFMA(wf, xf[0], acc[0][mt]);
      acc[1][mt] = MFMA(wf, xf[1], acc[1][mt]);
    }
  }

  // relu+bias, stage e into LDS ping 0 (row-major [16][72] bf16)
#pragma unroll
  for (int mt=0;mt<4;mt++){
    f32x4 be = *(const f32x4*)(b_enc + mt*16 + g*4);
#pragma unroll
    for (int u=0;u<2;u++){
      uint2 pk;
      float e0 = fmaxf(acc[u][mt][0]+be[0], 0.f), e1 = fmaxf(acc[u][mt][1]+be[1], 0.f);
      float e2 = fmaxf(acc[u][mt][2]+be[2], 0.f), e3 = fmaxf(acc[u][mt][3]+be[3], 0.f);
      pk.x = (unsigned)f2bf(e0) | ((unsigned)f2bf(e1)<<16);
      pk.y = (unsigned)f2bf(e2) | ((unsigned)f2bf(e3)<<16);
      *(uint2*)(&buf[wid][u][0][l15*72 + mt*16 + g*4]) = pk;
    }
  }
  __threadfence_block();

  // ======== Stage O: h = e @ W_obs + b_obs ========
  f32x4 hreg[2][4];
  {
    f32x4 hacc[2][4];
#pragma unroll
    for (int u=0;u<2;u++)
#pragma unroll
      for (int mt=0;mt<4;mt++) hacc[u][mt] = zero4();
    bf16x8 ef[2][2];
#pragma unroll
    for (int u=0;u<2;u++)
#pragma unroll
      for (int kt=0;kt<2;kt++)
        ef[u][kt] = *(const bf16x8*)(&buf[wid][u][0][l15*72 + kt*32 + g*8]);
#pragma unroll
    for (int kt=0;kt<2;kt++)
#pragma unroll
      for (int mt=0;mt<4;mt++){
        bf16x8 wf = pf[(OFF_OBS + kt*4 + mt)*64 + lane];
        hacc[0][mt] = MFMA(wf, ef[0][kt], hacc[0][mt]);
        hacc[1][mt] = MFMA(wf, ef[1][kt], hacc[1][mt]);
      }
#pragma unroll
    for (int mt=0;mt<4;mt++){
      f32x4 bo = *(const f32x4*)(b_obs + mt*16 + g*4);
#pragma unroll
      for (int u=0;u<2;u++)
#pragma unroll
        for (int j=0;j<4;j++) hreg[u][mt][j] = hacc[u][mt][j] + bo[j];
    }
  }

  // ======== GRU step 1 (c = 0): gi = bi, gh = h @ Wh + bh ========
#pragma unroll
  for (int u=0;u<2;u++)
#pragma unroll
    for (int mt=0;mt<4;mt++){
      uint2 pk;
      pk.x = (unsigned)f2bf(hreg[u][mt][0]) | ((unsigned)f2bf(hreg[u][mt][1])<<16);
      pk.y = (unsigned)f2bf(hreg[u][mt][2]) | ((unsigned)f2bf(hreg[u][mt][3])<<16);
      *(uint2*)(&buf[wid][u][1][l15*72 + mt*16 + g*4]) = pk;
    }
  __threadfence_block();
  {
    bf16x8 hf[2][2];
#pragma unroll
    for (int u=0;u<2;u++)
#pragma unroll
      for (int kt=0;kt<2;kt++)
        hf[u][kt] = *(const bf16x8*)(&buf[wid][u][1][l15*72 + kt*32 + g*8]);
#pragma unroll
    for (int mt=0;mt<4;mt++){
      f32x4 gr[2], gz[2], gn[2];
#pragma unroll
      for (int u=0;u<2;u++){ gr[u]=zero4(); gz[u]=zero4(); gn[u]=zero4(); }
#pragma unroll
      for (int kt=0;kt<2;kt++){
        bf16x8 wr_ = pf[(OFF_WH + kt*12 + mt    )*64 + lane];
        bf16x8 wz_ = pf[(OFF_WH + kt*12 + mt + 4)*64 + lane];
        bf16x8 wn_ = pf[(OFF_WH + kt*12 + mt + 8)*64 + lane];
#pragma unroll
        for (int u=0;u<2;u++){
          gr[u] = MFMA(wr_, hf[u][kt], gr[u]);
          gz[u] = MFMA(wz_, hf[u][kt], gz[u]);
          gn[u] = MFMA(wn_, hf[u][kt], gn[u]);
        }
      }
      f32x4 bir = *(const f32x4*)(bi + mt*16 + g*4);
      f32x4 bhr = *(const f32x4*)(bh + mt*16 + g*4);
      f32x4 biz = *(const f32x4*)(bi + 64 + mt*16 + g*4);
      f32x4 bhz = *(const f32x4*)(bh + 64 + mt*16 + g*4);
      f32x4 bin = *(const f32x4*)(bi + 128 + mt*16 + g*4);
      f32x4 bhn = *(const f32x4*)(bh + 128 + mt*16 + g*4);
#pragma unroll
      for (int u=0;u<2;u++)
#pragma unroll
        for (int j=0;j<4;j++){
          float r = sigmoidf_(gr[u][j] + bir[j] + bhr[j]);
          float z = sigmoidf_(gz[u][j] + biz[j] + bhz[j]);
          float n = tanhf_(bin[j] + r*(gn[u][j] + bhn[j]));
          hreg[u][mt][j] = (1.f - z)*n + z*hreg[u][mt][j];
        }
    }
  }

  // ======== agent mix: c = (sum_agents h - h)/8, then GRU step 2 ========
#pragma unroll
  for (int u=0;u<2;u++)
#pragma unroll
    for (int mt=0;mt<4;mt++){
      uint2 pk;
      pk.x = (unsigned)f2bf(hreg[u][mt][0]) | ((unsigned)f2bf(hreg[u][mt][1])<<16);
      pk.y = (unsigned)f2bf(hreg[u][mt][2]) | ((unsigned)f2bf(hreg[u][mt][3])<<16);
      *(uint2*)(&buf[wid][u][0][l15*72 + mt*16 + g*4]) = pk;   // ping 0 (e is dead)
    }
  __threadfence_block();
  // per-batch column sums S[2][64] per u-tile (tile = 2 batches of 8 rows)
#pragma unroll
  for (int u=0;u<2;u++){
    int b = lane>>5;
#pragma unroll
    for (int rep=0;rep<2;rep++){
      int c = (lane&31) + rep*32;
      float s = 0.f;
#pragma unroll
      for (int r=0;r<8;r++) s += bf2f(buf[wid][u][0][(b*8+r)*72 + c]);
      Sbuf[wid][u][b][c] = s;
    }
  }
  __threadfence_block();

  bf16x8 hf2[2][2], cf[2][2];
#pragma unroll
  for (int u=0;u<2;u++)
#pragma unroll
    for (int kt=0;kt<2;kt++){
      bf16x8 h8 = *(const bf16x8*)(&buf[wid][u][0][l15*72 + kt*32 + g*8]);
      hf2[u][kt] = h8;
      f32x4 s0 = *(const f32x4*)(&Sbuf[wid][u][l15>>3][kt*32 + g*8]);
      f32x4 s1 = *(const f32x4*)(&Sbuf[wid][u][l15>>3][kt*32 + g*8 + 4]);
      bf16x8 c8;
#pragma unroll
      for (int i=0;i<4;i++){
        float cv0 = (s0[i] - bf2f((unsigned short)h8[i]  )) * 0.125f;
        float cv1 = (s1[i] - bf2f((unsigned short)h8[i+4])) * 0.125f;
        c8[i]   = (short)f2bf(cv0);
        c8[i+4] = (short)f2bf(cv1);
      }
      cf[u][kt] = c8;
    }

#pragma unroll
  for (int mt=0;mt<4;mt++){
    f32x4 gr[2], gz[2], gni[2], gnh[2];
#pragma unroll
    for (int u=0;u<2;u++){ gr[u]=zero4(); gz[u]=zero4(); gni[u]=zero4(); gnh[u]=zero4(); }
#pragma unroll
    for (int kt=0;kt<2;kt++){
      bf16x8 whr = pf[(OFF_WH + kt*12 + mt    )*64 + lane];
      bf16x8 whz = pf[(OFF_WH + kt*12 + mt + 4)*64 + lane];
      bf16x8 whn = pf[(OFF_WH + kt*12 + mt + 8)*64 + lane];
      bf16x8 wir = pf[(OFF_WI + kt*12 + mt    )*64 + lane];
      bf16x8 wiz = pf[(OFF_WI + kt*12 + mt + 4)*64 + lane];
      bf16x8 win = pf[(OFF_WI + kt*12 + mt + 8)*64 + lane];
#pragma unroll
      for (int u=0;u<2;u++){
        gr[u]  = MFMA(whr, hf2[u][kt], gr[u]);
        gr[u]  = MFMA(wir, cf[u][kt],  gr[u]);
        gz[u]  = MFMA(whz, hf2[u][kt], gz[u]);
        gz[u]  = MFMA(wiz, cf[u][kt],  gz[u]);
        gnh[u] = MFMA(whn, hf2[u][kt], gnh[u]);
        gni[u] = MFMA(win, cf[u][kt],  gni[u]);
      }
    }
    f32x4 bir = *(const f32x4*)(bi + mt*16 + g*4);
    f32x4 bhr = *(const f32x4*)(bh + mt*16 + g*4);
    f32x4 biz = *(const f32x4*)(bi + 64 + mt*16 + g*4);
    f32x4 bhz = *(const f32x4*)(bh + 64 + mt*16 + g*4);
    f32x4 bin = *(const f32x4*)(bi + 128 + mt*16 + g*4);
    f32x4 bhn = *(const f32x4*)(bh + 128 + mt*16 + g*4);
#pragma unroll
    for (int u=0;u<2;u++)
#pragma unroll
      for (int j=0;j<4;j++){
        float r = sigmoidf_(gr[u][j] + bir[j] + bhr[j]);
        float z = sigmoidf_(gz[u][j] + biz[j] + bhz[j]);
        float n = tanhf_(gni[u][j] + bin[j] + r*(gnh[u][j] + bhn[j]));
        hreg[u][mt][j] = (1.f - z)*n + z*hreg[u][mt][j];
      }
  }

  // ======== decode: out = h @ W_dec + b_dec (shuffle reduce) ========
  float bd = bdec[0];
#pragma unroll
  for (int u=0;u<2;u++){
    float p = 0.f;
#pragma unroll
    for (int mt=0;mt<4;mt++){
      f32x4 wd = *(const f32x4*)(wdec + mt*16 + g*4);
#pragma unroll
      for (int j=0;j<4;j++) p += hreg[u][mt][j]*wd[j];
    }
    p += __shfl_xor(p, 16, 64);
    p += __shfl_xor(p, 32, 64);
    if (lane < 16) out[rb + u*16 + l15] = p + bd;
  }
}

// ---------------- launch ----------------
extern "C" void kernel_launch(void* const* d_in, const int* in_sizes, int n_in,
                              void* d_out, int out_size, void* d_ws, size_t ws_size,
                              hipStream_t stream) {
  (void)in_sizes; (void)n_in; (void)out_size; (void)ws_size;
  const float* obs   = (const float*)d_in[0];
  const float* act   = (const float*)d_in[1];
  const float* W_enc = (const float*)d_in[2];
  const float* b_enc = (const float*)d_in[3];
  const float* W_obs = (const float*)d_in[4];
  const float* b_obs = (const float*)d_in[5];
  const float* Wi    = (const float*)d_in[6];
  const float* bi    = (const float*)d_in[7];
  const float* Wh    = (const float*)d_in[8];
  const float* bh    = (const float*)d_in[9];
  const float* wdec  = (const float*)d_in[10];
  const float* bdec  = (const float*)d_in[11];
  unsigned short* pw = (unsigned short*)d_ws;   // 76 KiB of packed bf16 frags

  hipLaunchKernelGGL(pack_weights, dim3(NFRAG), dim3(64), 0, stream,
                     W_enc, W_obs, Wi, Wh, pw);
  hipLaunchKernelGGL(critic_main, dim3(NROW/128), dim3(256), 0, stream,
                     obs, act, b_enc, b_obs, bi, bh, wdec, bdec, pw, (float*)d_out);
}